// Round 5
// baseline (1425.979 us; speedup 1.0000x reference)
//
#include <hip/hip_runtime.h>

#define NUM_NODES 100000
#define IN_F 256
#define OUT_F 128
#define NSB 25              // superbuckets of 4096 nodes
#define NT 782              // tiles of 128 nodes
#define SPLIT_CHUNK 8192

typedef __attribute__((ext_vector_type(8))) short bf16x8;
typedef __attribute__((ext_vector_type(4))) float f32x4;

// bf16 round-to-nearest-even of one float.
__device__ inline unsigned short f2bf(float f) {
    unsigned u = __float_as_uint(f);
    u = (u + 0x7FFFu + ((u >> 16) & 1u)) >> 16;
    return (unsigned short)u;
}
__device__ inline float bf_lo(unsigned int u) { return __uint_as_float(u << 16); }
__device__ inline float bf_hi(unsigned int u) { return __uint_as_float(u & 0xFFFF0000u); }

// ---------------------------------------------------------------------------
// WT[n][k] = bf16(W[k][n])
// ---------------------------------------------------------------------------
__global__ __launch_bounds__(256) void convert_wt_kernel(
    const float* __restrict__ w, unsigned short* __restrict__ wt)
{
    int g = blockIdx.x * 256 + threadIdx.x;      // 0..32767 = k*128+n
    int k = g >> 7, n = g & 127;
    wt[n * 256 + k] = f2bf(w[g]);
}

// ---------------------------------------------------------------------------
// support = bf16(X @ W) via MFMA. 8 waves x 16-row strips = 128 rows/block.
// ---------------------------------------------------------------------------
__global__ __launch_bounds__(512) void gemm_mfma_kernel(
    const float* __restrict__ x, const unsigned short* __restrict__ wt,
    unsigned short* __restrict__ support_h)
{
    __shared__ unsigned short WT[128][264];

    const int tid = threadIdx.x;
    const uint4* src = reinterpret_cast<const uint4*>(wt);
#pragma unroll
    for (int i = 0; i < 8; ++i) {
        int j = tid + i * 512;
        int r = j >> 5;
        int c = (j & 31) << 3;
        *reinterpret_cast<uint4*>(&WT[r][c]) = src[j];
    }
    __syncthreads();

    const int wave = tid >> 6;
    const int lane = tid & 63;
    const int q = lane >> 4;
    const int r16 = lane & 15;
    const int strip_row = blockIdx.x * 128 + wave * 16;

    int arow = strip_row + r16;
    if (arow >= NUM_NODES) arow = NUM_NODES - 1;
    const float* xrow = x + (size_t)arow * IN_F + q * 8;

    f32x4 acc[8];
#pragma unroll
    for (int n = 0; n < 8; ++n) acc[n] = (f32x4){0.f, 0.f, 0.f, 0.f};

#pragma unroll
    for (int half = 0; half < 2; ++half) {
        float4 a[8];
#pragma unroll
        for (int g = 0; g < 4; ++g) {
            const float* p = xrow + half * 128 + g * 32;
            a[g * 2]     = *reinterpret_cast<const float4*>(p);
            a[g * 2 + 1] = *reinterpret_cast<const float4*>(p + 4);
        }
#pragma unroll
        for (int g = 0; g < 4; ++g) {
            const int k0 = half * 128 + g * 32;
            bf16x8 af;
            af[0] = (short)f2bf(a[g * 2].x);
            af[1] = (short)f2bf(a[g * 2].y);
            af[2] = (short)f2bf(a[g * 2].z);
            af[3] = (short)f2bf(a[g * 2].w);
            af[4] = (short)f2bf(a[g * 2 + 1].x);
            af[5] = (short)f2bf(a[g * 2 + 1].y);
            af[6] = (short)f2bf(a[g * 2 + 1].z);
            af[7] = (short)f2bf(a[g * 2 + 1].w);
#pragma unroll
            for (int n = 0; n < 8; ++n) {
                bf16x8 bfr = *reinterpret_cast<const bf16x8*>(
                    &WT[n * 16 + r16][k0 + q * 8]);
                acc[n] = __builtin_amdgcn_mfma_f32_16x16x32_bf16(
                    af, bfr, acc[n], 0, 0, 0);
            }
        }
    }

#pragma unroll
    for (int n = 0; n < 8; ++n) {
#pragma unroll
        for (int rr = 0; rr < 4; ++rr) {
            int grow = strip_row + q * 4 + rr;
            if (grow < NUM_NODES)
                support_h[(size_t)grow * OUT_F + n * 16 + r16] = f2bf(acc[n][rr]);
        }
    }
}

// ---------------------------------------------------------------------------
// Superbucket histogram (25 buckets of 4096 destination nodes)
// ---------------------------------------------------------------------------
__global__ __launch_bounds__(256) void sb_hist_kernel(
    const int* __restrict__ ei, int E, int* __restrict__ counts)
{
    __shared__ int h[32];
    if (threadIdx.x < 32) h[threadIdx.x] = 0;
    __syncthreads();
    int stride = gridDim.x * blockDim.x;
    for (int e = blockIdx.x * blockDim.x + threadIdx.x; e < E; e += stride)
        atomicAdd(&h[ei[E + e] >> 12], 1);
    __syncthreads();
    if (threadIdx.x < NSB) atomicAdd(&counts[threadIdx.x], h[threadIdx.x]);
}

// Tiny serial scan: gstart (exclusive, +total at [NSB]) and gcursor copy.
__global__ void sb_scan_kernel(const int* __restrict__ counts,
                               int* __restrict__ gstart, int* __restrict__ gcursor)
{
    if (threadIdx.x == 0) {
        int run = 0;
        for (int b = 0; b < NSB; ++b) {
            gstart[b] = run; gcursor[b] = run; run += counts[b];
        }
        gstart[NSB] = run;
    }
}

// ---------------------------------------------------------------------------
// Split edges into superbucket regions. Per block: 8192 edges, LDS hist +
// local counting sort, then per-bucket runs (avg 328 entries) copied out
// contiguously -> line-granular coalesced writes.
// rec = (row << 12) | (col & 4095)
// ---------------------------------------------------------------------------
__global__ __launch_bounds__(256) void sb_split_kernel(
    const int* __restrict__ ei, int E, int* __restrict__ gcursor,
    unsigned int* __restrict__ brec)
{
    __shared__ int hist[32], base[32], gbase[32], cur[32];
    __shared__ unsigned int sorted[SPLIT_CHUNK];
    const int t = threadIdx.x;
    const int e0 = blockIdx.x * SPLIT_CHUNK;

    if (t < 32) hist[t] = 0;
    __syncthreads();

#pragma unroll
    for (int i = 0; i < SPLIT_CHUNK / 256; ++i) {
        int e = e0 + i * 256 + t;
        if (e < E) atomicAdd(&hist[ei[E + e] >> 12], 1);
    }
    __syncthreads();

    if (t == 0) {
        int run = 0;
        for (int b = 0; b < NSB; ++b) { base[b] = run; run += hist[b]; }
    }
    __syncthreads();
    if (t < NSB) {
        gbase[t] = atomicAdd(&gcursor[t], hist[t]);
        cur[t] = base[t];
    }
    __syncthreads();

#pragma unroll
    for (int i = 0; i < SPLIT_CHUNK / 256; ++i) {
        int e = e0 + i * 256 + t;
        if (e < E) {
            int row = ei[e], col = ei[E + e];
            int b = col >> 12;
            int pos = atomicAdd(&cur[b], 1);
            sorted[pos] = ((unsigned)row << 12) | (unsigned)(col & 4095);
        }
    }
    __syncthreads();

    const int w = t >> 6, l = t & 63;
    for (int b = w; b < NSB; b += 4) {
        int n = hist[b], gb = gbase[b], bb = base[b];
        for (int j = l; j < n; j += 64)
            brec[gb + j] = sorted[bb + j];
    }
}

// ---------------------------------------------------------------------------
// Tile aggregate: 1 block per 128-node tile. 64 KB LDS fp32 accumulator
// (de-interleaved cols: [r][l]=col 2l, [r][64+l]=col 2l+1 -> ds_add 2-way
// bank = free). Waves scan the superbucket's record region, ballot-filter
// for this tile, batch up to 4 row-gathers for MLP, LDS-atomic accumulate.
// Epilogue: out = accum + support_self + bias (single coalesced write).
// ---------------------------------------------------------------------------
__global__ __launch_bounds__(512) void tile_agg_kernel(
    const unsigned int* __restrict__ support_bf,
    const unsigned int* __restrict__ brec,
    const int* __restrict__ gstart,
    const float* __restrict__ bias,
    float* __restrict__ out)
{
    __shared__ float accum[128][128];
    const int tid = threadIdx.x;
    const int lane = tid & 63;
    const int wid = tid >> 6;
    const int tile = blockIdx.x;
    const int node0 = tile << 7;
    const int sb = node0 >> 12;
    const unsigned int tl = (unsigned)(node0 >> 7) & 31u;

    float4 z = {0.f, 0.f, 0.f, 0.f};
#pragma unroll
    for (int i = 0; i < 8; ++i)
        *reinterpret_cast<float4*>(&accum[0][0] + (size_t)tid * 4 + (size_t)i * 2048) = z;
    __syncthreads();

    const int start = gstart[sb];
    const int end   = gstart[sb + 1];

    int base = start + wid * 64;
    unsigned int rec = 0;
    if (base + lane < end) rec = brec[base + lane];

    for (; base < end; base += 512) {
        // prefetch next chunk for this wave
        unsigned int rec_n = 0;
        int nidx = base + 512 + lane;
        if (nidx < end) rec_n = brec[nidx];

        bool valid = (base + lane < end) && (((rec >> 7) & 31u) == tl);
        unsigned long long mask = __ballot(valid);
        while (mask) {
            unsigned int w0, w1 = 0, w2 = 0, w3 = 0;
            int n1 = 0, n2 = 0, n3 = 0;
            { int i = __builtin_ctzll(mask); mask &= mask - 1; w0 = __shfl(rec, i); }
            if (mask) { int i = __builtin_ctzll(mask); mask &= mask - 1; w1 = __shfl(rec, i); n1 = 1; }
            if (mask) { int i = __builtin_ctzll(mask); mask &= mask - 1; w2 = __shfl(rec, i); n2 = 1; }
            if (mask) { int i = __builtin_ctzll(mask); mask &= mask - 1; w3 = __shfl(rec, i); n3 = 1; }
            unsigned int u0 = 0, u1 = 0, u2 = 0, u3 = 0;
            u0 = support_bf[(size_t)(w0 >> 12) * 64 + lane];
            if (n1) u1 = support_bf[(size_t)(w1 >> 12) * 64 + lane];
            if (n2) u2 = support_bf[(size_t)(w2 >> 12) * 64 + lane];
            if (n3) u3 = support_bf[(size_t)(w3 >> 12) * 64 + lane];
            {
                int c = w0 & 127;
                atomicAdd(&accum[c][lane],      bf_lo(u0));
                atomicAdd(&accum[c][64 + lane], bf_hi(u0));
            }
            if (n1) { int c = w1 & 127;
                atomicAdd(&accum[c][lane],      bf_lo(u1));
                atomicAdd(&accum[c][64 + lane], bf_hi(u1)); }
            if (n2) { int c = w2 & 127;
                atomicAdd(&accum[c][lane],      bf_lo(u2));
                atomicAdd(&accum[c][64 + lane], bf_hi(u2)); }
            if (n3) { int c = w3 & 127;
                atomicAdd(&accum[c][lane],      bf_lo(u3));
                atomicAdd(&accum[c][64 + lane], bf_hi(u3)); }
        }
        rec = rec_n;
    }
    __syncthreads();

    const int nrows = min(128, NUM_NODES - node0);
    float2 bi = *reinterpret_cast<const float2*>(bias + lane * 2);
    for (int r = wid; r < nrows; r += 8) {
        float a0 = accum[r][lane];
        float a1 = accum[r][64 + lane];
        unsigned int s = support_bf[(size_t)(node0 + r) * 64 + lane];
        float2 o = {a0 + bf_lo(s) + bi.x, a1 + bf_hi(s) + bi.y};
        *reinterpret_cast<float2*>(out + (size_t)(node0 + r) * OUT_F + lane * 2) = o;
    }
}

extern "C" void kernel_launch(void* const* d_in, const int* in_sizes, int n_in,
                              void* d_out, int out_size, void* d_ws, size_t ws_size,
                              hipStream_t stream) {
    const float* x    = (const float*)d_in[0];
    const float* w    = (const float*)d_in[1];
    const float* bias = (const float*)d_in[2];
    const int*   ei   = (const int*)d_in[3];
    float* out = (float*)d_out;
    const int E = in_sizes[3] / 2;
    const int N = NUM_NODES;

    // Workspace layout (~32.1 MB):
    //   support_bf : N*64 uints (bf16x2)   = 25.6 MB
    //   wt_bf      : 128*256 ushorts       = 64 KB
    //   counts     : 32 ints
    //   gstart     : 32 ints (NSB+1 used)
    //   gcursor    : 32 ints
    //   brec       : E uints               = 6.4 MB
    unsigned int* support_bf = (unsigned int*)d_ws;
    unsigned short* wt_bf = (unsigned short*)(support_bf + (size_t)N * 64);
    int* counts  = (int*)(wt_bf + 128 * 256);
    int* gstart  = counts + 32;
    int* gcursor = gstart + 32;
    unsigned int* brec = (unsigned int*)(gcursor + 32);

    // 1. GEMM: support = bf16(X @ W) via MFMA
    convert_wt_kernel<<<128, 256, 0, stream>>>(w, wt_bf);
    gemm_mfma_kernel<<<(N + 127) / 128, 512, 0, stream>>>(
        x, wt_bf, (unsigned short*)support_bf);

    // 2. Superbucket split of edges by destination
    hipMemsetAsync(counts, 0, 32 * sizeof(int), stream);
    sb_hist_kernel<<<256, 256, 0, stream>>>(ei, E, counts);
    sb_scan_kernel<<<1, 64, 0, stream>>>(counts, gstart, gcursor);
    sb_split_kernel<<<(E + SPLIT_CHUNK - 1) / SPLIT_CHUNK, 256, 0, stream>>>(
        ei, E, gcursor, brec);

    // 3. Destination-tiled aggregate (fused self + bias)
    tile_agg_kernel<<<NT, 512, 0, stream>>>(support_bf, brec, gstart, bias, out);
}